// Round 6
// baseline (159.230 us; speedup 1.0000x reference)
//
#include <hip/hip_runtime.h>
#include <cstdint>
#include <cstddef>

#define NN 4096
#define FDIM 256

typedef __attribute__((ext_vector_type(4))) float fx4;
typedef __attribute__((ext_vector_type(2))) float fx2;
typedef __attribute__((ext_vector_type(8))) short s8v;

__device__ inline uint16_t f2bf(float f) {
    union { float f; uint32_t u; } v; v.f = f;
    uint32_t u = v.u;
    uint32_t r = (u + 0x7FFFu + ((u >> 16) & 1u)) >> 16;
    return (uint16_t)r;
}

// ---------------- k_h: h = x @ W.T + b, plus a1/a2 chunk partials ----------------
// 64x64 tile, 4x4 micro (2 b128 LDS reads per 16 FMA - halves LDS/FLOP vs 2x4),
// single LDS buffer + register prefetch. grid(64,4)=256 blocks.
__global__ __launch_bounds__(256) void k_h(const float* __restrict__ x,
        const float* __restrict__ W, const float* __restrict__ bias,
        const float* __restrict__ att_w, float* __restrict__ h,
        float* __restrict__ a1p, float* __restrict__ a2p) {
    __shared__ __align__(16) float xs[64 * 68];   // [k][i], pad 68 + XOR swizzle
    __shared__ __align__(16) float wt[64 * 68];   // [k][f], pad 68 + XOR swizzle
    const int bi = blockIdx.x, bf = blockIdx.y;
    const int t = threadIdx.x;
    const int tx = t & 15, ty = t >> 4;
    float acc[4][4] = {};
    float rx[16], rw[16];
    #pragma unroll
    for (int u = 0; u < 16; ++u) {
        const int e = t + 256 * u, r = e >> 6, c = e & 63;
        rx[u] = x[(size_t)(bi * 64 + r) * 256 + c];
        rw[u] = W[(size_t)(bf * 64 + r) * 256 + c];
    }
    for (int p = 0; p < 4; ++p) {
        if (p) __syncthreads();
        #pragma unroll
        for (int u = 0; u < 16; ++u) {
            const int e = t + 256 * u, r = e >> 6, c = e & 63;
            const int sw = 8 * ((c & 7) ^ ((c >> 3) & 7));
            xs[c * 68 + (r ^ sw)] = rx[u];
            wt[c * 68 + (r ^ sw)] = rw[u];
        }
        __syncthreads();
        if (p < 3) {
            const int k0 = (p + 1) * 64;
            #pragma unroll
            for (int u = 0; u < 16; ++u) {
                const int e = t + 256 * u, r = e >> 6, c = e & 63;
                rx[u] = x[(size_t)(bi * 64 + r) * 256 + k0 + c];
                rw[u] = W[(size_t)(bf * 64 + r) * 256 + k0 + c];
            }
        }
        #pragma unroll 8
        for (int k = 0; k < 64; ++k) {
            const int sw = 8 * ((k & 7) ^ ((k >> 3) & 7));
            const fx4 av = *(const fx4*)(xs + k * 68 + ((ty * 4) ^ sw));
            const fx4 bv = *(const fx4*)(wt + k * 68 + ((tx * 4) ^ sw));
            #pragma unroll
            for (int u = 0; u < 4; ++u)
                #pragma unroll
                for (int v = 0; v < 4; ++v)
                    acc[u][v] += av[u] * bv[v];
        }
    }
    const fx4 bv = *(const fx4*)(bias + bf * 64 + tx * 4);
    const fx4 w1v = *(const fx4*)(att_w + bf * 64 + tx * 4);
    const fx4 w2v = *(const fx4*)(att_w + 256 + bf * 64 + tx * 4);
    #pragma unroll
    for (int u = 0; u < 4; ++u) {
        const int i = bi * 64 + ty * 4 + u;
        fx4 r;
        float s1 = 0.f, s2 = 0.f;
        #pragma unroll
        for (int v = 0; v < 4; ++v) {
            r[v] = acc[u][v] + bv[v];
            s1 += r[v] * w1v[v];
            s2 += r[v] * w2v[v];
        }
        *(fx4*)(h + (size_t)i * 256 + bf * 64 + tx * 4) = r;
        #pragma unroll
        for (int d = 8; d > 0; d >>= 1) {
            s1 += __shfl_down(s1, d, 16);
            s2 += __shfl_down(s2, d, 16);
        }
        if (tx == 0) {
            a1p[bf * NN + i] = s1;
            a2p[bf * NN + i] = s2;
        }
    }
}

// ---- k_prep: reduce a-partials, max/exp -> E1,E2, Sg=0, first-4096-edge scan ----
__global__ __launch_bounds__(1024) void k_prep(const float* __restrict__ a1p,
        const float* __restrict__ a2p, const int* __restrict__ adj,
        float* __restrict__ E1, float* __restrict__ E2,
        float* __restrict__ wraw, float* __restrict__ Sg) {
    __shared__ float E1s[NN];
    __shared__ float E2s[NN];
    __shared__ float red1[16], red2[16];
    __shared__ int wtot[16];
    __shared__ int base_s;
    const int t = threadIdx.x, lane = t & 63, wv = t >> 6;
    fx4 v1 = {0.f, 0.f, 0.f, 0.f}, v2 = {0.f, 0.f, 0.f, 0.f};
    #pragma unroll
    for (int bf = 0; bf < 4; ++bf) {
        v1 += *(const fx4*)(a1p + bf * NN + t * 4);
        v2 += *(const fx4*)(a2p + bf * NN + t * 4);
    }
    float m1 = fmaxf(fmaxf(v1[0], v1[1]), fmaxf(v1[2], v1[3]));
    float m2 = fmaxf(fmaxf(v2[0], v2[1]), fmaxf(v2[2], v2[3]));
    #pragma unroll
    for (int d = 32; d > 0; d >>= 1) {
        m1 = fmaxf(m1, __shfl_down(m1, d));
        m2 = fmaxf(m2, __shfl_down(m2, d));
    }
    if (lane == 0) { red1[wv] = m1; red2[wv] = m2; }
    __syncthreads();
    if (t == 0) {
        float mm1 = -1e30f, mm2 = -1e30f;
        for (int k = 0; k < 16; ++k) {
            mm1 = fmaxf(mm1, red1[k]);
            mm2 = fmaxf(mm2, red2[k]);
        }
        red1[0] = mm1; red2[0] = mm2;
        *Sg = 0.f;
        base_s = 0;
    }
    __syncthreads();
    const float M1 = red1[0], M2 = red2[0];
    fx4 e1v, e2v, z4 = {0.f, 0.f, 0.f, 0.f};
    #pragma unroll
    for (int j = 0; j < 4; ++j) {
        e1v[j] = expf(v1[j] - M1);
        e2v[j] = expf(v2[j] - M2);
    }
    *(fx4*)(E1s + t * 4) = e1v;
    *(fx4*)(E2s + t * 4) = e2v;
    *(fx4*)(E1 + t * 4) = e1v;
    *(fx4*)(E2 + t * 4) = e2v;
    *(fx4*)(wraw + t * 4) = z4;
    __syncthreads();
    for (int row = 0; row < NN; ++row) {
        const int base = base_s;           // uniform
        if (base >= NN) break;             // uniform break
        const int4 a = ((const int4*)(adj + (size_t)row * NN))[t];
        const int vj[4] = {a.x, a.y, a.z, a.w};
        int cnt = 0;
        #pragma unroll
        for (int j = 0; j < 4; ++j) cnt += (vj[j] == 1);
        int inc = cnt;
        #pragma unroll
        for (int d = 1; d < 64; d <<= 1) {
            const int y = __shfl_up(inc, d);
            if (lane >= d) inc += y;
        }
        if (lane == 63) wtot[wv] = inc;
        __syncthreads();                   // B1
        int wbase = 0, total = 0;
        #pragma unroll
        for (int w = 0; w < 16; ++w) {
            const int xw = wtot[w];
            total += xw;
            wbase += (w < wv) ? xw : 0;
        }
        if (t == 0) base_s = base + total;
        int r = base + wbase + inc - cnt;
        if (cnt && r < NN) {
            const float e1 = E1s[row];
            #pragma unroll
            for (int j = 0; j < 4; ++j) {
                if (vj[j] == 1) {
                    if (r < NN) wraw[r] = e1 * E2s[t * 4 + j];
                    ++r;
                }
            }
        }
        __syncthreads();                   // B2
    }
}

// -------- k_g: gt[f][j] = bf16(wraw[j]*h[j][f]), cb-XOR swizzled per 64-j chunk --------
// Within each 64-col chunk, the 16B block cb (8 shorts) of row f is stored at
// cb ^ (f&7). k_fused's global_load_lds copies chunks linearly; its B-frag read
// applies the same XOR -> conflict-free without padding. grid(64,4), 64x64 tiles.
__global__ __launch_bounds__(256) void k_g(const float* __restrict__ h,
        const float* __restrict__ wraw, uint16_t* __restrict__ gt) {
    __shared__ float tile[64 * 65];
    const int bj = blockIdx.x, bf = blockIdx.y;
    const int j0 = bj * 64, f0 = bf * 64;
    const int t = threadIdx.x;
    #pragma unroll
    for (int p = 0; p < 16; ++p) {
        const int e = t + 256 * p;
        const int jl = e >> 6, fl = e & 63;
        tile[jl * 65 + fl] = h[(size_t)(j0 + jl) * 256 + f0 + fl] * wraw[j0 + jl];
    }
    __syncthreads();
    #pragma unroll
    for (int u = 0; u < 2; ++u) {
        const int unit = t + 256 * u;      // 512 units: 64 f x 8 cb
        const int fl = unit >> 3, cb = unit & 7;
        const int phys_cb = cb ^ (fl & 7);
        s8v v;
        #pragma unroll
        for (int lo = 0; lo < 8; ++lo)
            v[lo] = (short)f2bf(tile[(cb * 8 + lo) * 65 + fl]);
        *(s8v*)(gt + (size_t)(f0 + fl) * NN + j0 + phys_cb * 8) = v;
    }
}

// -------- k_fused: part = A @ G (bf16 MFMA, split-K) + S via E2 side-tile --------
// Gs staged by global_load_lds width=16 (DMA, linear unpadded rows; bank spread
// comes from the gt cb-XOR swizzle). As staged explicitly (int->bf16 convert).
// GsS[16][72]: row 0 = E2 chunk (bf16), rows 1..15 = 0; wave 3 computes the
// S-column tile: C[i][256] = adj_row . E2; epilogue S += E1[i]*C[i][256].
__global__ __launch_bounds__(256) void k_fused(const int* __restrict__ adj,
        const uint16_t* __restrict__ gt, const float* __restrict__ E1,
        const float* __restrict__ E2, uint16_t* __restrict__ part,
        float* __restrict__ Sg, int krange) {
    __shared__ __align__(16) uint16_t As[64 * 72];     // padded (explicit writes)
    __shared__ __align__(16) uint16_t Gs[256 * 64];    // linear (DMA target)
    __shared__ __align__(16) uint16_t GsS[16 * 72];    // E2 row + zeros
    const int ib = blockIdx.x, ks = blockIdx.y;
    const int t = threadIdx.x;
    const int wv = t >> 6, lane = t & 63;
    const int q = lane >> 4, m16 = lane & 15;
    const int i0 = ib * 64, k0 = ks * krange;
    const int ksteps = krange >> 6;
    fx4 acc[4][4];
    #pragma unroll
    for (int a = 0; a < 4; ++a)
        #pragma unroll
        for (int b = 0; b < 4; ++b) acc[a][b] = (fx4){0.f, 0.f, 0.f, 0.f};
    fx4 accS[4];
    #pragma unroll
    for (int a = 0; a < 4; ++a) accS[a] = (fx4){0.f, 0.f, 0.f, 0.f};
    // zero GsS rows 1..15 once (covered by first in-loop barrier)
    for (int e = t; e < 15 * 72; e += 256) GsS[72 + e] = 0;

    const int fr = lane >> 3, cb = lane & 7;           // DMA lane mapping
    for (int step = 0; step < ksteps; ++step) {
        const int kk = k0 + step * 64;
        // ---- As: adj -> bf16 {0,1} via bit-trick ----
        #pragma unroll
        for (int p = 0; p < 4; ++p) {
            const int r = p * 16 + (t >> 4);
            const int c4 = (t & 15) * 4;
            const int4 a = *(const int4*)(adj + (size_t)(i0 + r) * NN + kk + c4);
            uint2 w;
            w.x = (uint32_t)(a.x | (a.y << 16)) * 0x3F80u;
            w.y = (uint32_t)(a.z | (a.w << 16)) * 0x3F80u;
            *(uint2*)(&As[r * 72 + c4]) = w;
        }
        // ---- Gs: DMA 1 KB (8 rows) per instr, 8 instrs/wave ----
        #pragma unroll
        for (int p = 0; p < 8; ++p) {
            const int f0 = wv * 64 + p * 8;
            const uint16_t* gp = gt + (size_t)(f0 + fr) * NN + kk + cb * 8;
            __builtin_amdgcn_global_load_lds(
                (const __attribute__((address_space(1))) uint32_t*)gp,
                (__attribute__((address_space(3))) uint32_t*)(Gs + f0 * 64),
                16, 0, 0);
        }
        // ---- GsS row 0: E2 chunk in bf16 ----
        if (t < 8) {
            const float* e2p = E2 + kk + t * 8;
            uint32_t* dst = (uint32_t*)(&GsS[t * 8]);
            #pragma unroll
            for (int j = 0; j < 4; ++j)
                dst[j] = (uint32_t)f2bf(e2p[2 * j]) |
                         ((uint32_t)f2bf(e2p[2 * j + 1]) << 16);
        }
        __syncthreads();
        s8v afr[4][2];
        #pragma unroll
        for (int it = 0; it < 4; ++it)
            #pragma unroll
            for (int kh = 0; kh < 2; ++kh)
                afr[it][kh] = *(const s8v*)(As + (it * 16 + m16) * 72 + kh * 32 + q * 8);
        #pragma unroll
        for (int ft = 0; ft < 4; ++ft) {
            #pragma unroll
            for (int kh = 0; kh < 2; ++kh) {
                const int row = wv * 64 + ft * 16 + m16;
                const int pcb = ((kh << 2) | q) ^ (m16 & 7);   // un-swizzle
                const s8v bfr = *(const s8v*)(Gs + row * 64 + pcb * 8);
                #pragma unroll
                for (int it = 0; it < 4; ++it)
                    acc[it][ft] = __builtin_amdgcn_mfma_f32_16x16x32_bf16(
                        afr[it][kh], bfr, acc[it][ft], 0, 0, 0);
            }
        }
        if (wv == 3) {
            #pragma unroll
            for (int kh = 0; kh < 2; ++kh) {
                const s8v bfrS = *(const s8v*)(GsS + m16 * 72 + kh * 32 + q * 8);
                #pragma unroll
                for (int it = 0; it < 4; ++it)
                    accS[it] = __builtin_amdgcn_mfma_f32_16x16x32_bf16(
                        afr[it][kh], bfrS, accS[it], 0, 0, 0);
            }
        }
        __syncthreads();
    }
    if (wv == 3) {
        float s_local = 0.f;
        #pragma unroll
        for (int it = 0; it < 4; ++it)
            #pragma unroll
            for (int r = 0; r < 4; ++r)
                s_local += accS[it][r] * E1[i0 + it * 16 + q * 4 + r];
        #pragma unroll
        for (int d = 32; d > 0; d >>= 1) s_local += __shfl_down(s_local, d);
        if (lane == 0) atomicAdd(Sg, s_local);
    }
    // bf16 partials; C/D layout: col=lane&15, row=(lane>>4)*4+reg
    uint16_t* dst = part + (size_t)ks * NN * FDIM;
    #pragma unroll
    for (int it = 0; it < 4; ++it) {
        #pragma unroll
        for (int ft = 0; ft < 4; ++ft) {
            const int f = wv * 64 + ft * 16 + m16;
            #pragma unroll
            for (int r = 0; r < 4; ++r) {
                const int i = i0 + it * 16 + q * 4 + r;
                dst[(size_t)i * FDIM + f] = f2bf(acc[it][ft][r]);
            }
        }
    }
}

// -------- k_out: out = relu(sum_k part_k) / S (bf16 partials, 8 f/thread) --------
__global__ __launch_bounds__(256) void k_out(const uint16_t* __restrict__ part,
        const float* __restrict__ Sg, float* __restrict__ out, int nsplit) {
    const size_t idx = ((size_t)blockIdx.x * 256 + threadIdx.x) * 8;
    const float inv = 1.0f / (*Sg);
    float s[8] = {};
    for (int k = 0; k < nsplit; ++k) {
        const s8v v = *(const s8v*)(part + (size_t)k * NN * FDIM + idx);
        #pragma unroll
        for (int j = 0; j < 8; ++j) {
            union { uint32_t u; float f; } cv;
            cv.u = ((uint32_t)(uint16_t)v[j]) << 16;
            s[j] += cv.f;
        }
    }
    fx4 r0, r1;
    #pragma unroll
    for (int j = 0; j < 4; ++j) {
        r0[j] = fmaxf(s[j], 0.f) * inv;
        r1[j] = fmaxf(s[4 + j], 0.f) * inv;
    }
    *(fx4*)(out + idx) = r0;
    *(fx4*)(out + idx + 4) = r1;
}

extern "C" void kernel_launch(void* const* d_in, const int* in_sizes, int n_in,
                              void* d_out, int out_size, void* d_ws, size_t ws_size,
                              hipStream_t stream) {
    const float* x     = (const float*)d_in[0];
    const int*   adj   = (const int*)d_in[1];
    const float* W     = (const float*)d_in[2];
    const float* bias  = (const float*)d_in[3];
    const float* att_w = (const float*)d_in[4];
    // att_b (d_in[5]) cancels exactly in the softmax — unused.
    float* out = (float*)d_out;
    char* ws = (char*)d_ws;
    float*    h    = (float*)(ws + 0);                    // 4 MB
    uint16_t* gt   = (uint16_t*)(ws + (size_t)4194304);   // 2 MB
    float*    a1p  = (float*)(ws + 6291456);              // 64 KB (4 x 4096)
    float*    a2p  = (float*)(ws + 6356992);              // 64 KB
    float*    E1   = (float*)(ws + 6422528);              // 16 KB
    float*    E2   = (float*)(ws + 6438912);              // 16 KB
    float*    wraw = (float*)(ws + 6455296);              // 16 KB
    float*    Sg   = (float*)(ws + 6471680);              // 256 B
    uint16_t* part = (uint16_t*)(ws + 6471936);           // splitk * 2 MB (bf16)

    const size_t avail = (ws_size > 6471936) ? (ws_size - 6471936) : 0;
    int splitk = 1;
    while (splitk < 8 &&
           (size_t)(splitk * 2) * NN * FDIM * sizeof(uint16_t) <= avail)
        splitk <<= 1;
    const int krange = NN / splitk;

    k_h    <<<dim3(64, 4), 256, 0, stream>>>(x, W, bias, att_w, h, a1p, a2p);
    k_prep <<<dim3(1), 1024, 0, stream>>>(a1p, a2p, adj, E1, E2, wraw, Sg);
    k_g    <<<dim3(64, 4), 256, 0, stream>>>(h, wraw, gt);
    k_fused<<<dim3(64, splitk), 256, 0, stream>>>(adj, gt, E1, E2, part, Sg, krange);
    k_out  <<<dim3(512), 256, 0, stream>>>(part, Sg, out, splitk);
}

// Round 7
// 151.080 us; speedup vs baseline: 1.0539x; 1.0539x over previous
//
#include <hip/hip_runtime.h>
#include <cstdint>
#include <cstddef>

#define NN 4096
#define FDIM 256

typedef __attribute__((ext_vector_type(4))) float fx4;
typedef __attribute__((ext_vector_type(2))) float fx2;
typedef __attribute__((ext_vector_type(8))) short s8v;

__device__ inline uint16_t f2bf(float f) {
    union { float f; uint32_t u; } v; v.f = f;
    uint32_t u = v.u;
    uint32_t r = (u + 0x7FFFu + ((u >> 16) & 1u)) >> 16;
    return (uint16_t)r;
}

// ---------------- k_h: h = x @ W.T + b, plus a1/a2 chunk partials ----------------
// R5 version: 32x64 tiles, dbuf + reg prefetch, grid(128,4)=512 -> 2 blocks/CU.
__global__ __launch_bounds__(256) void k_h(const float* __restrict__ x,
        const float* __restrict__ W, const float* __restrict__ bias,
        const float* __restrict__ att_w, float* __restrict__ h,
        float* __restrict__ a1p, float* __restrict__ a2p) {
    __shared__ __align__(16) float xs[2][64 * 34];
    __shared__ __align__(16) float wt[2][64 * 68];
    const int bi = blockIdx.x, bf = blockIdx.y;
    const int t = threadIdx.x;
    const int tx = t & 15, ty = t >> 4;
    float acc[2][4] = {};
    float rx[8], rw[16];
    #pragma unroll
    for (int u = 0; u < 8; ++u) {
        const int e = t + 256 * u, r = e >> 6, c = e & 63;
        rx[u] = x[(size_t)(bi * 32 + r) * 256 + c];
    }
    #pragma unroll
    for (int u = 0; u < 16; ++u) {
        const int e = t + 256 * u, r = e >> 6, c = e & 63;
        rw[u] = W[(size_t)(bf * 64 + r) * 256 + c];
    }
    for (int p = 0; p < 4; ++p) {
        float* xb = xs[p & 1];
        float* wb = wt[p & 1];
        #pragma unroll
        for (int u = 0; u < 8; ++u) {
            const int e = t + 256 * u, r = e >> 6, c = e & 63;
            xb[c * 34 + r] = rx[u];
        }
        #pragma unroll
        for (int u = 0; u < 16; ++u) {
            const int e = t + 256 * u, r = e >> 6, c = e & 63;
            const int sw = 8 * ((c & 7) ^ ((c >> 3) & 7));
            wb[c * 68 + (r ^ sw)] = rw[u];
        }
        __syncthreads();
        if (p < 3) {
            const int k0 = (p + 1) * 64;
            #pragma unroll
            for (int u = 0; u < 8; ++u) {
                const int e = t + 256 * u, r = e >> 6, c = e & 63;
                rx[u] = x[(size_t)(bi * 32 + r) * 256 + k0 + c];
            }
            #pragma unroll
            for (int u = 0; u < 16; ++u) {
                const int e = t + 256 * u, r = e >> 6, c = e & 63;
                rw[u] = W[(size_t)(bf * 64 + r) * 256 + k0 + c];
            }
        }
        #pragma unroll 16
        for (int k = 0; k < 64; ++k) {
            const int sw = 8 * ((k & 7) ^ ((k >> 3) & 7));
            const fx2 av = *(const fx2*)(xb + k * 34 + ty * 2);
            const fx4 bv = *(const fx4*)(wb + k * 68 + ((tx * 4) ^ sw));
            #pragma unroll
            for (int u = 0; u < 2; ++u)
                #pragma unroll
                for (int v = 0; v < 4; ++v)
                    acc[u][v] += av[u] * bv[v];
        }
    }
    const fx4 bv = *(const fx4*)(bias + bf * 64 + tx * 4);
    const fx4 w1v = *(const fx4*)(att_w + bf * 64 + tx * 4);
    const fx4 w2v = *(const fx4*)(att_w + 256 + bf * 64 + tx * 4);
    #pragma unroll
    for (int u = 0; u < 2; ++u) {
        const int i = bi * 32 + ty * 2 + u;
        fx4 r;
        float s1 = 0.f, s2 = 0.f;
        #pragma unroll
        for (int v = 0; v < 4; ++v) {
            r[v] = acc[u][v] + bv[v];
            s1 += r[v] * w1v[v];
            s2 += r[v] * w2v[v];
        }
        *(fx4*)(h + (size_t)i * 256 + bf * 64 + tx * 4) = r;
        #pragma unroll
        for (int d = 8; d > 0; d >>= 1) {
            s1 += __shfl_down(s1, d, 16);
            s2 += __shfl_down(s2, d, 16);
        }
        if (tx == 0) {
            a1p[bf * NN + i] = s1;
            a2p[bf * NN + i] = s2;
        }
    }
}

// ---- k_prep: reduce a-partials, max/exp -> E1,E2, Sg=0, first-4096-edge scan ----
__global__ __launch_bounds__(1024) void k_prep(const float* __restrict__ a1p,
        const float* __restrict__ a2p, const int* __restrict__ adj,
        float* __restrict__ E1, float* __restrict__ E2,
        float* __restrict__ wraw, float* __restrict__ Sg) {
    __shared__ float E1s[NN];
    __shared__ float E2s[NN];
    __shared__ float red1[16], red2[16];
    __shared__ int wtot[16];
    __shared__ int base_s;
    const int t = threadIdx.x, lane = t & 63, wv = t >> 6;
    fx4 v1 = {0.f, 0.f, 0.f, 0.f}, v2 = {0.f, 0.f, 0.f, 0.f};
    #pragma unroll
    for (int bf = 0; bf < 4; ++bf) {
        v1 += *(const fx4*)(a1p + bf * NN + t * 4);
        v2 += *(const fx4*)(a2p + bf * NN + t * 4);
    }
    float m1 = fmaxf(fmaxf(v1[0], v1[1]), fmaxf(v1[2], v1[3]));
    float m2 = fmaxf(fmaxf(v2[0], v2[1]), fmaxf(v2[2], v2[3]));
    #pragma unroll
    for (int d = 32; d > 0; d >>= 1) {
        m1 = fmaxf(m1, __shfl_down(m1, d));
        m2 = fmaxf(m2, __shfl_down(m2, d));
    }
    if (lane == 0) { red1[wv] = m1; red2[wv] = m2; }
    __syncthreads();
    if (t == 0) {
        float mm1 = -1e30f, mm2 = -1e30f;
        for (int k = 0; k < 16; ++k) {
            mm1 = fmaxf(mm1, red1[k]);
            mm2 = fmaxf(mm2, red2[k]);
        }
        red1[0] = mm1; red2[0] = mm2;
        *Sg = 0.f;
        base_s = 0;
    }
    __syncthreads();
    const float M1 = red1[0], M2 = red2[0];
    fx4 e1v, e2v, z4 = {0.f, 0.f, 0.f, 0.f};
    #pragma unroll
    for (int j = 0; j < 4; ++j) {
        e1v[j] = expf(v1[j] - M1);
        e2v[j] = expf(v2[j] - M2);
    }
    *(fx4*)(E1s + t * 4) = e1v;
    *(fx4*)(E2s + t * 4) = e2v;
    *(fx4*)(E1 + t * 4) = e1v;
    *(fx4*)(E2 + t * 4) = e2v;
    *(fx4*)(wraw + t * 4) = z4;
    __syncthreads();
    for (int row = 0; row < NN; ++row) {
        const int base = base_s;           // uniform
        if (base >= NN) break;             // uniform break
        const int4 a = ((const int4*)(adj + (size_t)row * NN))[t];
        const int vj[4] = {a.x, a.y, a.z, a.w};
        int cnt = 0;
        #pragma unroll
        for (int j = 0; j < 4; ++j) cnt += (vj[j] == 1);
        int inc = cnt;
        #pragma unroll
        for (int d = 1; d < 64; d <<= 1) {
            const int y = __shfl_up(inc, d);
            if (lane >= d) inc += y;
        }
        if (lane == 63) wtot[wv] = inc;
        __syncthreads();                   // B1
        int wbase = 0, total = 0;
        #pragma unroll
        for (int w = 0; w < 16; ++w) {
            const int xw = wtot[w];
            total += xw;
            wbase += (w < wv) ? xw : 0;
        }
        if (t == 0) base_s = base + total;
        int r = base + wbase + inc - cnt;
        if (cnt && r < NN) {
            const float e1 = E1s[row];
            #pragma unroll
            for (int j = 0; j < 4; ++j) {
                if (vj[j] == 1) {
                    if (r < NN) wraw[r] = e1 * E2s[t * 4 + j];
                    ++r;
                }
            }
        }
        __syncthreads();                   // B2
    }
}

// -------- k_g: gt[f][j] = bf16(wraw[j]*h[j][f]), cb-XOR swizzled per 64-j chunk --------
// 64j x 32f tiles, grid(64,8)=512 blocks (2/CU). Within each 64-col chunk, the
// 16B block cb of row f is stored at cb ^ (f&7); k_fused's DMA copies chunks
// linearly and its B-frag read applies the same XOR -> conflict-free, no pad.
__global__ __launch_bounds__(256) void k_g(const float* __restrict__ h,
        const float* __restrict__ wraw, uint16_t* __restrict__ gt) {
    __shared__ float tile[64 * 33];
    const int bj = blockIdx.x, bf = blockIdx.y;   // 64 x 8
    const int j0 = bj * 64, f0 = bf * 32;
    const int t = threadIdx.x;
    #pragma unroll
    for (int p = 0; p < 8; ++p) {
        const int e = t + 256 * p;
        const int jl = e >> 5, fl = e & 31;
        tile[jl * 33 + fl] = h[(size_t)(j0 + jl) * 256 + f0 + fl] * wraw[j0 + jl];
    }
    __syncthreads();
    {
        const int fl = t >> 3, cb = t & 7;        // 32 f x 8 cb
        const int phys_cb = cb ^ (fl & 7);
        s8v v;
        #pragma unroll
        for (int lo = 0; lo < 8; ++lo)
            v[lo] = (short)f2bf(tile[(cb * 8 + lo) * 33 + fl]);
        *(s8v*)(gt + (size_t)(f0 + fl) * NN + j0 + phys_cb * 8) = v;
    }
}

// -------- k_fused: part = A @ G (bf16 MFMA, split-K) + S via E2 side-tile --------
// Gs staged by global_load_lds width=16 (DMA, linear unpadded rows; bank spread
// from the gt cb-XOR swizzle). As staged explicitly (int->bf16 bit-trick).
// GsS[16][72]: row 0 = E2 chunk (bf16), rows 1..15 = 0; wave 3 computes the
// S-column tile: C[i][256] = adj_row . E2; epilogue S += E1[i]*C[i][256].
__global__ __launch_bounds__(256) void k_fused(const int* __restrict__ adj,
        const uint16_t* __restrict__ gt, const float* __restrict__ E1,
        const float* __restrict__ E2, uint16_t* __restrict__ part,
        float* __restrict__ Sg, int krange) {
    __shared__ __align__(16) uint16_t As[64 * 72];     // padded (explicit writes)
    __shared__ __align__(16) uint16_t Gs[256 * 64];    // linear (DMA target)
    __shared__ __align__(16) uint16_t GsS[16 * 72];    // E2 row + zeros
    const int ib = blockIdx.x, ks = blockIdx.y;
    const int t = threadIdx.x;
    const int wv = t >> 6, lane = t & 63;
    const int q = lane >> 4, m16 = lane & 15;
    const int i0 = ib * 64, k0 = ks * krange;
    const int ksteps = krange >> 6;
    fx4 acc[4][4];
    #pragma unroll
    for (int a = 0; a < 4; ++a)
        #pragma unroll
        for (int b = 0; b < 4; ++b) acc[a][b] = (fx4){0.f, 0.f, 0.f, 0.f};
    fx4 accS[4];
    #pragma unroll
    for (int a = 0; a < 4; ++a) accS[a] = (fx4){0.f, 0.f, 0.f, 0.f};
    for (int e = t; e < 15 * 72; e += 256) GsS[72 + e] = 0;

    const int fr = lane >> 3, cb = lane & 7;           // DMA lane mapping
    for (int step = 0; step < ksteps; ++step) {
        const int kk = k0 + step * 64;
        // ---- As: adj -> bf16 {0,1} via bit-trick ----
        #pragma unroll
        for (int p = 0; p < 4; ++p) {
            const int r = p * 16 + (t >> 4);
            const int c4 = (t & 15) * 4;
            const int4 a = *(const int4*)(adj + (size_t)(i0 + r) * NN + kk + c4);
            uint2 w;
            w.x = (uint32_t)(a.x | (a.y << 16)) * 0x3F80u;
            w.y = (uint32_t)(a.z | (a.w << 16)) * 0x3F80u;
            *(uint2*)(&As[r * 72 + c4]) = w;
        }
        // ---- Gs: DMA 1 KB (8 rows) per instr, 8 instrs/wave ----
        #pragma unroll
        for (int p = 0; p < 8; ++p) {
            const int f0 = wv * 64 + p * 8;
            const uint16_t* gp = gt + (size_t)(f0 + fr) * NN + kk + cb * 8;
            __builtin_amdgcn_global_load_lds(
                (const __attribute__((address_space(1))) uint32_t*)gp,
                (__attribute__((address_space(3))) uint32_t*)(Gs + f0 * 64),
                16, 0, 0);
        }
        // ---- GsS row 0: E2 chunk in bf16 ----
        if (t < 8) {
            const float* e2p = E2 + kk + t * 8;
            uint32_t* dst = (uint32_t*)(&GsS[t * 8]);
            #pragma unroll
            for (int j = 0; j < 4; ++j)
                dst[j] = (uint32_t)f2bf(e2p[2 * j]) |
                         ((uint32_t)f2bf(e2p[2 * j + 1]) << 16);
        }
        __syncthreads();
        s8v afr[4][2];
        #pragma unroll
        for (int it = 0; it < 4; ++it)
            #pragma unroll
            for (int kh = 0; kh < 2; ++kh)
                afr[it][kh] = *(const s8v*)(As + (it * 16 + m16) * 72 + kh * 32 + q * 8);
        #pragma unroll
        for (int ft = 0; ft < 4; ++ft) {
            #pragma unroll
            for (int kh = 0; kh < 2; ++kh) {
                const int row = wv * 64 + ft * 16 + m16;
                const int pcb = ((kh << 2) | q) ^ (m16 & 7);   // un-swizzle
                const s8v bfr = *(const s8v*)(Gs + row * 64 + pcb * 8);
                #pragma unroll
                for (int it = 0; it < 4; ++it)
                    acc[it][ft] = __builtin_amdgcn_mfma_f32_16x16x32_bf16(
                        afr[it][kh], bfr, acc[it][ft], 0, 0, 0);
            }
        }
        if (wv == 3) {
            #pragma unroll
            for (int kh = 0; kh < 2; ++kh) {
                const s8v bfrS = *(const s8v*)(GsS + m16 * 72 + kh * 32 + q * 8);
                #pragma unroll
                for (int it = 0; it < 4; ++it)
                    accS[it] = __builtin_amdgcn_mfma_f32_16x16x32_bf16(
                        afr[it][kh], bfrS, accS[it], 0, 0, 0);
            }
        }
        __syncthreads();
    }
    if (wv == 3) {
        float s_local = 0.f;
        #pragma unroll
        for (int it = 0; it < 4; ++it)
            #pragma unroll
            for (int r = 0; r < 4; ++r)
                s_local += accS[it][r] * E1[i0 + it * 16 + q * 4 + r];
        #pragma unroll
        for (int d = 32; d > 0; d >>= 1) s_local += __shfl_down(s_local, d);
        if (lane == 0) atomicAdd(Sg, s_local);
    }
    // bf16 partials; C/D layout: col=lane&15, row=(lane>>4)*4+reg
    uint16_t* dst = part + (size_t)ks * NN * FDIM;
    #pragma unroll
    for (int it = 0; it < 4; ++it) {
        #pragma unroll
        for (int ft = 0; ft < 4; ++ft) {
            const int f = wv * 64 + ft * 16 + m16;
            #pragma unroll
            for (int r = 0; r < 4; ++r) {
                const int i = i0 + it * 16 + q * 4 + r;
                dst[(size_t)i * FDIM + f] = f2bf(acc[it][ft][r]);
            }
        }
    }
}

// -------- k_out: out = relu(sum_k part_k) / S (bf16 partials, 8 f/thread) --------
__global__ __launch_bounds__(256) void k_out(const uint16_t* __restrict__ part,
        const float* __restrict__ Sg, float* __restrict__ out, int nsplit) {
    const size_t idx = ((size_t)blockIdx.x * 256 + threadIdx.x) * 8;
    const float inv = 1.0f / (*Sg);
    float s[8] = {};
    for (int k = 0; k < nsplit; ++k) {
        const s8v v = *(const s8v*)(part + (size_t)k * NN * FDIM + idx);
        #pragma unroll
        for (int j = 0; j < 8; ++j) {
            union { uint32_t u; float f; } cv;
            cv.u = ((uint32_t)(uint16_t)v[j]) << 16;
            s[j] += cv.f;
        }
    }
    fx4 r0, r1;
    #pragma unroll
    for (int j = 0; j < 4; ++j) {
        r0[j] = fmaxf(s[j], 0.f) * inv;
        r1[j] = fmaxf(s[4 + j], 0.f) * inv;
    }
    *(fx4*)(out + idx) = r0;
    *(fx4*)(out + idx + 4) = r1;
}

extern "C" void kernel_launch(void* const* d_in, const int* in_sizes, int n_in,
                              void* d_out, int out_size, void* d_ws, size_t ws_size,
                              hipStream_t stream) {
    const float* x     = (const float*)d_in[0];
    const int*   adj   = (const int*)d_in[1];
    const float* W     = (const float*)d_in[2];
    const float* bias  = (const float*)d_in[3];
    const float* att_w = (const float*)d_in[4];
    // att_b (d_in[5]) cancels exactly in the softmax — unused.
    float* out = (float*)d_out;
    char* ws = (char*)d_ws;
    float*    h    = (float*)(ws + 0);                    // 4 MB
    uint16_t* gt   = (uint16_t*)(ws + (size_t)4194304);   // 2 MB
    float*    a1p  = (float*)(ws + 6291456);              // 64 KB (4 x 4096)
    float*    a2p  = (float*)(ws + 6356992);              // 64 KB
    float*    E1   = (float*)(ws + 6422528);              // 16 KB
    float*    E2   = (float*)(ws + 6438912);              // 16 KB
    float*    wraw = (float*)(ws + 6455296);              // 16 KB
    float*    Sg   = (float*)(ws + 6471680);              // 256 B
    uint16_t* part = (uint16_t*)(ws + 6471936);           // splitk * 2 MB (bf16)

    const size_t avail = (ws_size > 6471936) ? (ws_size - 6471936) : 0;
    int splitk = 1;
    while (splitk < 8 &&
           (size_t)(splitk * 2) * NN * FDIM * sizeof(uint16_t) <= avail)
        splitk <<= 1;
    const int krange = NN / splitk;

    k_h    <<<dim3(128, 4), 256, 0, stream>>>(x, W, bias, att_w, h, a1p, a2p);
    k_prep <<<dim3(1), 1024, 0, stream>>>(a1p, a2p, adj, E1, E2, wraw, Sg);
    k_g    <<<dim3(64, 8), 256, 0, stream>>>(h, wraw, gt);
    k_fused<<<dim3(64, splitk), 256, 0, stream>>>(adj, gt, E1, E2, part, Sg, krange);
    k_out  <<<dim3(512), 256, 0, stream>>>(part, Sg, out, splitk);
}

// Round 8
// 149.960 us; speedup vs baseline: 1.0618x; 1.0075x over previous
//
#include <hip/hip_runtime.h>
#include <cstdint>
#include <cstddef>

#define NN 4096
#define FDIM 256

typedef __attribute__((ext_vector_type(4))) float fx4;
typedef __attribute__((ext_vector_type(2))) float fx2;
typedef __attribute__((ext_vector_type(8))) short s8v;

__device__ inline uint16_t f2bf(float f) {
    union { float f; uint32_t u; } v; v.f = f;
    uint32_t u = v.u;
    uint32_t r = (u + 0x7FFFu + ((u >> 16) & 1u)) >> 16;
    return (uint16_t)r;
}

// ---------------- k_h: h = x @ W.T + b, plus a1/a2 chunk partials ----------------
// 64x64 tile, 4x4 micro (2 B LDS/FMA vs 3 for 2x4), 512 threads (8 waves/CU =
// R5-equivalent occupancy), dbuf + reg prefetch, intra-block K-split: waves 0-3
// take k[0,32), waves 4-7 k[32,64) per phase; halves merged via LDS at the end.
__global__ __launch_bounds__(512) void k_h(const float* __restrict__ x,
        const float* __restrict__ W, const float* __restrict__ bias,
        const float* __restrict__ att_w, float* __restrict__ h,
        float* __restrict__ a1p, float* __restrict__ a2p) {
    __shared__ __align__(16) float xs[2][64 * 68];
    __shared__ __align__(16) float wt[2][64 * 68];
    const int bi = blockIdx.x, bf = blockIdx.y;
    const int t = threadIdx.x;
    const int t256 = t & 255;
    const int kh = t >> 8;                         // K-half: 0 or 1
    const int tx = t256 & 15, ty = t256 >> 4;      // f-group, i-group
    float acc[4][4] = {};
    float rx[8], rw[8];
    #pragma unroll
    for (int u = 0; u < 8; ++u) {
        const int e = t + 512 * u, r = e >> 6, c = e & 63;
        rx[u] = x[(size_t)(bi * 64 + r) * 256 + c];
        rw[u] = W[(size_t)(bf * 64 + r) * 256 + c];
    }
    for (int p = 0; p < 4; ++p) {
        float* xb = xs[p & 1];
        float* wb = wt[p & 1];
        #pragma unroll
        for (int u = 0; u < 8; ++u) {
            const int e = t + 512 * u, r = e >> 6, c = e & 63;
            const int sw = 8 * ((c & 7) ^ ((c >> 3) & 7));
            xb[c * 68 + (r ^ sw)] = rx[u];
            wb[c * 68 + (r ^ sw)] = rw[u];
        }
        __syncthreads();
        if (p < 3) {
            const int k0 = (p + 1) * 64;
            #pragma unroll
            for (int u = 0; u < 8; ++u) {
                const int e = t + 512 * u, r = e >> 6, c = e & 63;
                rx[u] = x[(size_t)(bi * 64 + r) * 256 + k0 + c];
                rw[u] = W[(size_t)(bf * 64 + r) * 256 + k0 + c];
            }
        }
        #pragma unroll 8
        for (int k = 0; k < 32; ++k) {
            const int kk = kh * 32 + k;
            const int sw = 8 * ((kk & 7) ^ ((kk >> 3) & 7));
            const fx4 av = *(const fx4*)(xb + kk * 68 + ((ty * 4) ^ sw));
            const fx4 bv = *(const fx4*)(wb + kk * 68 + ((tx * 4) ^ sw));
            #pragma unroll
            for (int u = 0; u < 4; ++u)
                #pragma unroll
                for (int v = 0; v < 4; ++v)
                    acc[u][v] += av[u] * bv[v];
        }
        // dbuf: next phase writes the other buffer; one barrier per phase.
    }
    // merge the two K-half accumulators via LDS (reuse xs[0]: 4096 floats)
    __syncthreads();
    float* cbuf = xs[0];
    if (kh == 1) {
        #pragma unroll
        for (int u = 0; u < 4; ++u)
            *(fx4*)(cbuf + t256 * 16 + u * 4) = *(const fx4*)(&acc[u][0]);
    }
    __syncthreads();
    if (kh == 0) {
        #pragma unroll
        for (int u = 0; u < 4; ++u) {
            const fx4 o = *(const fx4*)(cbuf + t256 * 16 + u * 4);
            #pragma unroll
            for (int v = 0; v < 4; ++v) acc[u][v] += o[v];
        }
        const fx4 bv = *(const fx4*)(bias + bf * 64 + tx * 4);
        const fx4 w1v = *(const fx4*)(att_w + bf * 64 + tx * 4);
        const fx4 w2v = *(const fx4*)(att_w + 256 + bf * 64 + tx * 4);
        #pragma unroll
        for (int u = 0; u < 4; ++u) {
            const int i = bi * 64 + ty * 4 + u;
            fx4 r;
            float s1 = 0.f, s2 = 0.f;
            #pragma unroll
            for (int v = 0; v < 4; ++v) {
                r[v] = acc[u][v] + bv[v];
                s1 += r[v] * w1v[v];
                s2 += r[v] * w2v[v];
            }
            *(fx4*)(h + (size_t)i * 256 + bf * 64 + tx * 4) = r;
            #pragma unroll
            for (int d = 8; d > 0; d >>= 1) {
                s1 += __shfl_down(s1, d, 16);
                s2 += __shfl_down(s2, d, 16);
            }
            if (tx == 0) {
                a1p[bf * NN + i] = s1;
                a2p[bf * NN + i] = s2;
            }
        }
    }
}

// ---- k_prep: reduce a-partials, max/exp -> E1,E2, Sg=0, first-4096-edge scan ----
__global__ __launch_bounds__(1024) void k_prep(const float* __restrict__ a1p,
        const float* __restrict__ a2p, const int* __restrict__ adj,
        float* __restrict__ E1, float* __restrict__ E2,
        float* __restrict__ wraw, float* __restrict__ Sg) {
    __shared__ float E1s[NN];
    __shared__ float E2s[NN];
    __shared__ float red1[16], red2[16];
    __shared__ int wtot[16];
    __shared__ int base_s;
    const int t = threadIdx.x, lane = t & 63, wv = t >> 6;
    fx4 v1 = {0.f, 0.f, 0.f, 0.f}, v2 = {0.f, 0.f, 0.f, 0.f};
    #pragma unroll
    for (int bf = 0; bf < 4; ++bf) {
        v1 += *(const fx4*)(a1p + bf * NN + t * 4);
        v2 += *(const fx4*)(a2p + bf * NN + t * 4);
    }
    float m1 = fmaxf(fmaxf(v1[0], v1[1]), fmaxf(v1[2], v1[3]));
    float m2 = fmaxf(fmaxf(v2[0], v2[1]), fmaxf(v2[2], v2[3]));
    #pragma unroll
    for (int d = 32; d > 0; d >>= 1) {
        m1 = fmaxf(m1, __shfl_down(m1, d));
        m2 = fmaxf(m2, __shfl_down(m2, d));
    }
    if (lane == 0) { red1[wv] = m1; red2[wv] = m2; }
    __syncthreads();
    if (t == 0) {
        float mm1 = -1e30f, mm2 = -1e30f;
        for (int k = 0; k < 16; ++k) {
            mm1 = fmaxf(mm1, red1[k]);
            mm2 = fmaxf(mm2, red2[k]);
        }
        red1[0] = mm1; red2[0] = mm2;
        *Sg = 0.f;
        base_s = 0;
    }
    __syncthreads();
    const float M1 = red1[0], M2 = red2[0];
    fx4 e1v, e2v, z4 = {0.f, 0.f, 0.f, 0.f};
    #pragma unroll
    for (int j = 0; j < 4; ++j) {
        e1v[j] = expf(v1[j] - M1);
        e2v[j] = expf(v2[j] - M2);
    }
    *(fx4*)(E1s + t * 4) = e1v;
    *(fx4*)(E2s + t * 4) = e2v;
    *(fx4*)(E1 + t * 4) = e1v;
    *(fx4*)(E2 + t * 4) = e2v;
    *(fx4*)(wraw + t * 4) = z4;
    __syncthreads();
    for (int row = 0; row < NN; ++row) {
        const int base = base_s;           // uniform
        if (base >= NN) break;             // uniform break
        const int4 a = ((const int4*)(adj + (size_t)row * NN))[t];
        const int vj[4] = {a.x, a.y, a.z, a.w};
        int cnt = 0;
        #pragma unroll
        for (int j = 0; j < 4; ++j) cnt += (vj[j] == 1);
        int inc = cnt;
        #pragma unroll
        for (int d = 1; d < 64; d <<= 1) {
            const int y = __shfl_up(inc, d);
            if (lane >= d) inc += y;
        }
        if (lane == 63) wtot[wv] = inc;
        __syncthreads();                   // B1
        int wbase = 0, total = 0;
        #pragma unroll
        for (int w = 0; w < 16; ++w) {
            const int xw = wtot[w];
            total += xw;
            wbase += (w < wv) ? xw : 0;
        }
        if (t == 0) base_s = base + total;
        int r = base + wbase + inc - cnt;
        if (cnt && r < NN) {
            const float e1 = E1s[row];
            #pragma unroll
            for (int j = 0; j < 4; ++j) {
                if (vj[j] == 1) {
                    if (r < NN) wraw[r] = e1 * E2s[t * 4 + j];
                    ++r;
                }
            }
        }
        __syncthreads();                   // B2
    }
}

// -------- k_g: gt[f][j] = bf16(wraw[j]*h[j][f]), cb-XOR swizzled per 64-j chunk --------
// 64j x 32f tiles, grid(64,8)=512 blocks (2/CU). Within each 64-col chunk, the
// 16B block cb of row f is stored at cb ^ (f&7); k_fused's DMA copies chunks
// linearly and its B-frag read applies the same XOR -> conflict-free, no pad.
__global__ __launch_bounds__(256) void k_g(const float* __restrict__ h,
        const float* __restrict__ wraw, uint16_t* __restrict__ gt) {
    __shared__ float tile[64 * 33];
    const int bj = blockIdx.x, bf = blockIdx.y;   // 64 x 8
    const int j0 = bj * 64, f0 = bf * 32;
    const int t = threadIdx.x;
    #pragma unroll
    for (int p = 0; p < 8; ++p) {
        const int e = t + 256 * p;
        const int jl = e >> 5, fl = e & 31;
        tile[jl * 33 + fl] = h[(size_t)(j0 + jl) * 256 + f0 + fl] * wraw[j0 + jl];
    }
    __syncthreads();
    {
        const int fl = t >> 3, cb = t & 7;        // 32 f x 8 cb
        const int phys_cb = cb ^ (fl & 7);
        s8v v;
        #pragma unroll
        for (int lo = 0; lo < 8; ++lo)
            v[lo] = (short)f2bf(tile[(cb * 8 + lo) * 33 + fl]);
        *(s8v*)(gt + (size_t)(f0 + fl) * NN + j0 + phys_cb * 8) = v;
    }
}

// -------- k_fused: part = A @ G (bf16 MFMA, split-K) + S via E2 side-tile --------
// Gs staged by global_load_lds width=16 (DMA, linear unpadded rows; bank spread
// from the gt cb-XOR swizzle). As staged explicitly (int->bf16 bit-trick).
// GsS[16][72]: row 0 = E2 chunk (bf16), rows 1..15 = 0; wave 3 computes the
// S-column tile: C[i][256] = adj_row . E2; epilogue S += E1[i]*C[i][256].
__global__ __launch_bounds__(256) void k_fused(const int* __restrict__ adj,
        const uint16_t* __restrict__ gt, const float* __restrict__ E1,
        const float* __restrict__ E2, uint16_t* __restrict__ part,
        float* __restrict__ Sg, int krange) {
    __shared__ __align__(16) uint16_t As[64 * 72];     // padded (explicit writes)
    __shared__ __align__(16) uint16_t Gs[256 * 64];    // linear (DMA target)
    __shared__ __align__(16) uint16_t GsS[16 * 72];    // E2 row + zeros
    const int ib = blockIdx.x, ks = blockIdx.y;
    const int t = threadIdx.x;
    const int wv = t >> 6, lane = t & 63;
    const int q = lane >> 4, m16 = lane & 15;
    const int i0 = ib * 64, k0 = ks * krange;
    const int ksteps = krange >> 6;
    fx4 acc[4][4];
    #pragma unroll
    for (int a = 0; a < 4; ++a)
        #pragma unroll
        for (int b = 0; b < 4; ++b) acc[a][b] = (fx4){0.f, 0.f, 0.f, 0.f};
    fx4 accS[4];
    #pragma unroll
    for (int a = 0; a < 4; ++a) accS[a] = (fx4){0.f, 0.f, 0.f, 0.f};
    for (int e = t; e < 15 * 72; e += 256) GsS[72 + e] = 0;

    const int fr = lane >> 3, cb = lane & 7;           // DMA lane mapping
    for (int step = 0; step < ksteps; ++step) {
        const int kk = k0 + step * 64;
        // ---- As: adj -> bf16 {0,1} via bit-trick ----
        #pragma unroll
        for (int p = 0; p < 4; ++p) {
            const int r = p * 16 + (t >> 4);
            const int c4 = (t & 15) * 4;
            const int4 a = *(const int4*)(adj + (size_t)(i0 + r) * NN + kk + c4);
            uint2 w;
            w.x = (uint32_t)(a.x | (a.y << 16)) * 0x3F80u;
            w.y = (uint32_t)(a.z | (a.w << 16)) * 0x3F80u;
            *(uint2*)(&As[r * 72 + c4]) = w;
        }
        // ---- Gs: DMA 1 KB (8 rows) per instr, 8 instrs/wave ----
        #pragma unroll
        for (int p = 0; p < 8; ++p) {
            const int f0 = wv * 64 + p * 8;
            const uint16_t* gp = gt + (size_t)(f0 + fr) * NN + kk + cb * 8;
            __builtin_amdgcn_global_load_lds(
                (const __attribute__((address_space(1))) uint32_t*)gp,
                (__attribute__((address_space(3))) uint32_t*)(Gs + f0 * 64),
                16, 0, 0);
        }
        // ---- GsS row 0: E2 chunk in bf16 ----
        if (t < 8) {
            const float* e2p = E2 + kk + t * 8;
            uint32_t* dst = (uint32_t*)(&GsS[t * 8]);
            #pragma unroll
            for (int j = 0; j < 4; ++j)
                dst[j] = (uint32_t)f2bf(e2p[2 * j]) |
                         ((uint32_t)f2bf(e2p[2 * j + 1]) << 16);
        }
        __syncthreads();
        s8v afr[4][2];
        #pragma unroll
        for (int it = 0; it < 4; ++it)
            #pragma unroll
            for (int kh = 0; kh < 2; ++kh)
                afr[it][kh] = *(const s8v*)(As + (it * 16 + m16) * 72 + kh * 32 + q * 8);
        #pragma unroll
        for (int ft = 0; ft < 4; ++ft) {
            #pragma unroll
            for (int kh = 0; kh < 2; ++kh) {
                const int row = wv * 64 + ft * 16 + m16;
                const int pcb = ((kh << 2) | q) ^ (m16 & 7);   // un-swizzle
                const s8v bfr = *(const s8v*)(Gs + row * 64 + pcb * 8);
                #pragma unroll
                for (int it = 0; it < 4; ++it)
                    acc[it][ft] = __builtin_amdgcn_mfma_f32_16x16x32_bf16(
                        afr[it][kh], bfr, acc[it][ft], 0, 0, 0);
            }
        }
        if (wv == 3) {
            #pragma unroll
            for (int kh = 0; kh < 2; ++kh) {
                const s8v bfrS = *(const s8v*)(GsS + m16 * 72 + kh * 32 + q * 8);
                #pragma unroll
                for (int it = 0; it < 4; ++it)
                    accS[it] = __builtin_amdgcn_mfma_f32_16x16x32_bf16(
                        afr[it][kh], bfrS, accS[it], 0, 0, 0);
            }
        }
        __syncthreads();
    }
    if (wv == 3) {
        float s_local = 0.f;
        #pragma unroll
        for (int it = 0; it < 4; ++it)
            #pragma unroll
            for (int r = 0; r < 4; ++r)
                s_local += accS[it][r] * E1[i0 + it * 16 + q * 4 + r];
        #pragma unroll
        for (int d = 32; d > 0; d >>= 1) s_local += __shfl_down(s_local, d);
        if (lane == 0) atomicAdd(Sg, s_local);
    }
    // bf16 partials; C/D layout: col=lane&15, row=(lane>>4)*4+reg
    uint16_t* dst = part + (size_t)ks * NN * FDIM;
    #pragma unroll
    for (int it = 0; it < 4; ++it) {
        #pragma unroll
        for (int ft = 0; ft < 4; ++ft) {
            const int f = wv * 64 + ft * 16 + m16;
            #pragma unroll
            for (int r = 0; r < 4; ++r) {
                const int i = i0 + it * 16 + q * 4 + r;
                dst[(size_t)i * FDIM + f] = f2bf(acc[it][ft][r]);
            }
        }
    }
}

// -------- k_out: out = relu(sum_k part_k) / S (bf16 partials, 8 f/thread) --------
__global__ __launch_bounds__(256) void k_out(const uint16_t* __restrict__ part,
        const float* __restrict__ Sg, float* __restrict__ out, int nsplit) {
    const size_t idx = ((size_t)blockIdx.x * 256 + threadIdx.x) * 8;
    const float inv = 1.0f / (*Sg);
    float s[8] = {};
    for (int k = 0; k < nsplit; ++k) {
        const s8v v = *(const s8v*)(part + (size_t)k * NN * FDIM + idx);
        #pragma unroll
        for (int j = 0; j < 8; ++j) {
            union { uint32_t u; float f; } cv;
            cv.u = ((uint32_t)(uint16_t)v[j]) << 16;
            s[j] += cv.f;
        }
    }
    fx4 r0, r1;
    #pragma unroll
    for (int j = 0; j < 4; ++j) {
        r0[j] = fmaxf(s[j], 0.f) * inv;
        r1[j] = fmaxf(s[4 + j], 0.f) * inv;
    }
    *(fx4*)(out + idx) = r0;
    *(fx4*)(out + idx + 4) = r1;
}

extern "C" void kernel_launch(void* const* d_in, const int* in_sizes, int n_in,
                              void* d_out, int out_size, void* d_ws, size_t ws_size,
                              hipStream_t stream) {
    const float* x     = (const float*)d_in[0];
    const int*   adj   = (const int*)d_in[1];
    const float* W     = (const float*)d_in[2];
    const float* bias  = (const float*)d_in[3];
    const float* att_w = (const float*)d_in[4];
    // att_b (d_in[5]) cancels exactly in the softmax — unused.
    float* out = (float*)d_out;
    char* ws = (char*)d_ws;
    float*    h    = (float*)(ws + 0);                    // 4 MB
    uint16_t* gt   = (uint16_t*)(ws + (size_t)4194304);   // 2 MB
    float*    a1p  = (float*)(ws + 6291456);              // 64 KB (4 x 4096)
    float*    a2p  = (float*)(ws + 6356992);              // 64 KB
    float*    E1   = (float*)(ws + 6422528);              // 16 KB
    float*    E2   = (float*)(ws + 6438912);              // 16 KB
    float*    wraw = (float*)(ws + 6455296);              // 16 KB
    float*    Sg   = (float*)(ws + 6471680);              // 256 B
    uint16_t* part = (uint16_t*)(ws + 6471936);           // splitk * 2 MB (bf16)

    const size_t avail = (ws_size > 6471936) ? (ws_size - 6471936) : 0;
    int splitk = 1;
    while (splitk < 8 &&
           (size_t)(splitk * 2) * NN * FDIM * sizeof(uint16_t) <= avail)
        splitk <<= 1;
    const int krange = NN / splitk;

    k_h    <<<dim3(64, 4), 512, 0, stream>>>(x, W, bias, att_w, h, a1p, a2p);
    k_prep <<<dim3(1), 1024, 0, stream>>>(a1p, a2p, adj, E1, E2, wraw, Sg);
    k_g    <<<dim3(64, 8), 256, 0, stream>>>(h, wraw, gt);
    k_fused<<<dim3(64, splitk), 256, 0, stream>>>(adj, gt, E1, E2, part, Sg, krange);
    k_out  <<<dim3(512), 256, 0, stream>>>(part, Sg, out, splitk);
}

// Round 9
// 146.019 us; speedup vs baseline: 1.0905x; 1.0270x over previous
//
#include <hip/hip_runtime.h>
#include <cstdint>
#include <cstddef>

#define NN 4096
#define FDIM 256

typedef __attribute__((ext_vector_type(4))) float fx4;
typedef __attribute__((ext_vector_type(2))) float fx2;
typedef __attribute__((ext_vector_type(8))) short s8v;

__device__ inline uint16_t f2bf(float f) {
    union { float f; uint32_t u; } v; v.f = f;
    uint32_t u = v.u;
    uint32_t r = (u + 0x7FFFu + ((u >> 16) & 1u)) >> 16;
    return (uint16_t)r;
}

// ---------------- k_h: h = x @ W.T + b, plus a1/a2 chunk partials ----------------
// 64x64 tile, 4x4 micro, 512 threads (8 waves/CU), dbuf + reg prefetch,
// intra-block K-split: waves 0-3 take k[0,32), waves 4-7 k[32,64) per phase.
__global__ __launch_bounds__(512) void k_h(const float* __restrict__ x,
        const float* __restrict__ W, const float* __restrict__ bias,
        const float* __restrict__ att_w, float* __restrict__ h,
        float* __restrict__ a1p, float* __restrict__ a2p) {
    __shared__ __align__(16) float xs[2][64 * 68];
    __shared__ __align__(16) float wt[2][64 * 68];
    const int bi = blockIdx.x, bf = blockIdx.y;
    const int t = threadIdx.x;
    const int t256 = t & 255;
    const int kh = t >> 8;                         // K-half: 0 or 1
    const int tx = t256 & 15, ty = t256 >> 4;      // f-group, i-group
    float acc[4][4] = {};
    float rx[8], rw[8];
    #pragma unroll
    for (int u = 0; u < 8; ++u) {
        const int e = t + 512 * u, r = e >> 6, c = e & 63;
        rx[u] = x[(size_t)(bi * 64 + r) * 256 + c];
        rw[u] = W[(size_t)(bf * 64 + r) * 256 + c];
    }
    for (int p = 0; p < 4; ++p) {
        float* xb = xs[p & 1];
        float* wb = wt[p & 1];
        #pragma unroll
        for (int u = 0; u < 8; ++u) {
            const int e = t + 512 * u, r = e >> 6, c = e & 63;
            const int sw = 8 * ((c & 7) ^ ((c >> 3) & 7));
            xb[c * 68 + (r ^ sw)] = rx[u];
            wb[c * 68 + (r ^ sw)] = rw[u];
        }
        __syncthreads();
        if (p < 3) {
            const int k0 = (p + 1) * 64;
            #pragma unroll
            for (int u = 0; u < 8; ++u) {
                const int e = t + 512 * u, r = e >> 6, c = e & 63;
                rx[u] = x[(size_t)(bi * 64 + r) * 256 + k0 + c];
                rw[u] = W[(size_t)(bf * 64 + r) * 256 + k0 + c];
            }
        }
        #pragma unroll 8
        for (int k = 0; k < 32; ++k) {
            const int kk = kh * 32 + k;
            const int sw = 8 * ((kk & 7) ^ ((kk >> 3) & 7));
            const fx4 av = *(const fx4*)(xb + kk * 68 + ((ty * 4) ^ sw));
            const fx4 bv = *(const fx4*)(wb + kk * 68 + ((tx * 4) ^ sw));
            #pragma unroll
            for (int u = 0; u < 4; ++u)
                #pragma unroll
                for (int v = 0; v < 4; ++v)
                    acc[u][v] += av[u] * bv[v];
        }
    }
    __syncthreads();
    float* cbuf = xs[0];
    if (kh == 1) {
        #pragma unroll
        for (int u = 0; u < 4; ++u)
            *(fx4*)(cbuf + t256 * 16 + u * 4) = *(const fx4*)(&acc[u][0]);
    }
    __syncthreads();
    if (kh == 0) {
        #pragma unroll
        for (int u = 0; u < 4; ++u) {
            const fx4 o = *(const fx4*)(cbuf + t256 * 16 + u * 4);
            #pragma unroll
            for (int v = 0; v < 4; ++v) acc[u][v] += o[v];
        }
        const fx4 bv = *(const fx4*)(bias + bf * 64 + tx * 4);
        const fx4 w1v = *(const fx4*)(att_w + bf * 64 + tx * 4);
        const fx4 w2v = *(const fx4*)(att_w + 256 + bf * 64 + tx * 4);
        #pragma unroll
        for (int u = 0; u < 4; ++u) {
            const int i = bi * 64 + ty * 4 + u;
            fx4 r;
            float s1 = 0.f, s2 = 0.f;
            #pragma unroll
            for (int v = 0; v < 4; ++v) {
                r[v] = acc[u][v] + bv[v];
                s1 += r[v] * w1v[v];
                s2 += r[v] * w2v[v];
            }
            *(fx4*)(h + (size_t)i * 256 + bf * 64 + tx * 4) = r;
            #pragma unroll
            for (int d = 8; d > 0; d >>= 1) {
                s1 += __shfl_down(s1, d, 16);
                s2 += __shfl_down(s2, d, 16);
            }
            if (tx == 0) {
                a1p[bf * NN + i] = s1;
                a2p[bf * NN + i] = s2;
            }
        }
    }
}

// ---- k_prep: reduce a-partials, max/exp -> E1,E2, Sg=0, first-4096-edge scan ----
__global__ __launch_bounds__(1024) void k_prep(const float* __restrict__ a1p,
        const float* __restrict__ a2p, const int* __restrict__ adj,
        float* __restrict__ E1, float* __restrict__ E2,
        float* __restrict__ wraw, float* __restrict__ Sg) {
    __shared__ float E1s[NN];
    __shared__ float E2s[NN];
    __shared__ float red1[16], red2[16];
    __shared__ int wtot[16];
    __shared__ int base_s;
    const int t = threadIdx.x, lane = t & 63, wv = t >> 6;
    fx4 v1 = {0.f, 0.f, 0.f, 0.f}, v2 = {0.f, 0.f, 0.f, 0.f};
    #pragma unroll
    for (int bf = 0; bf < 4; ++bf) {
        v1 += *(const fx4*)(a1p + bf * NN + t * 4);
        v2 += *(const fx4*)(a2p + bf * NN + t * 4);
    }
    float m1 = fmaxf(fmaxf(v1[0], v1[1]), fmaxf(v1[2], v1[3]));
    float m2 = fmaxf(fmaxf(v2[0], v2[1]), fmaxf(v2[2], v2[3]));
    #pragma unroll
    for (int d = 32; d > 0; d >>= 1) {
        m1 = fmaxf(m1, __shfl_down(m1, d));
        m2 = fmaxf(m2, __shfl_down(m2, d));
    }
    if (lane == 0) { red1[wv] = m1; red2[wv] = m2; }
    __syncthreads();
    if (t == 0) {
        float mm1 = -1e30f, mm2 = -1e30f;
        for (int k = 0; k < 16; ++k) {
            mm1 = fmaxf(mm1, red1[k]);
            mm2 = fmaxf(mm2, red2[k]);
        }
        red1[0] = mm1; red2[0] = mm2;
        *Sg = 0.f;
        base_s = 0;
    }
    __syncthreads();
    const float M1 = red1[0], M2 = red2[0];
    fx4 e1v, e2v, z4 = {0.f, 0.f, 0.f, 0.f};
    #pragma unroll
    for (int j = 0; j < 4; ++j) {
        e1v[j] = expf(v1[j] - M1);
        e2v[j] = expf(v2[j] - M2);
    }
    *(fx4*)(E1s + t * 4) = e1v;
    *(fx4*)(E2s + t * 4) = e2v;
    *(fx4*)(E1 + t * 4) = e1v;
    *(fx4*)(E2 + t * 4) = e2v;
    *(fx4*)(wraw + t * 4) = z4;
    __syncthreads();
    for (int row = 0; row < NN; ++row) {
        const int base = base_s;           // uniform
        if (base >= NN) break;             // uniform break
        const int4 a = ((const int4*)(adj + (size_t)row * NN))[t];
        const int vj[4] = {a.x, a.y, a.z, a.w};
        int cnt = 0;
        #pragma unroll
        for (int j = 0; j < 4; ++j) cnt += (vj[j] == 1);
        int inc = cnt;
        #pragma unroll
        for (int d = 1; d < 64; d <<= 1) {
            const int y = __shfl_up(inc, d);
            if (lane >= d) inc += y;
        }
        if (lane == 63) wtot[wv] = inc;
        __syncthreads();                   // B1
        int wbase = 0, total = 0;
        #pragma unroll
        for (int w = 0; w < 16; ++w) {
            const int xw = wtot[w];
            total += xw;
            wbase += (w < wv) ? xw : 0;
        }
        if (t == 0) base_s = base + total;
        int r = base + wbase + inc - cnt;
        if (cnt && r < NN) {
            const float e1 = E1s[row];
            #pragma unroll
            for (int j = 0; j < 4; ++j) {
                if (vj[j] == 1) {
                    if (r < NN) wraw[r] = e1 * E2s[t * 4 + j];
                    ++r;
                }
            }
        }
        __syncthreads();                   // B2
    }
}

// -------- k_g: gt[f][j] = bf16(wraw[j]*h[j][f]), cb-XOR swizzled per 64-j chunk --------
__global__ __launch_bounds__(256) void k_g(const float* __restrict__ h,
        const float* __restrict__ wraw, uint16_t* __restrict__ gt) {
    __shared__ float tile[64 * 33];
    const int bj = blockIdx.x, bf = blockIdx.y;   // 64 x 8
    const int j0 = bj * 64, f0 = bf * 32;
    const int t = threadIdx.x;
    #pragma unroll
    for (int p = 0; p < 8; ++p) {
        const int e = t + 256 * p;
        const int jl = e >> 5, fl = e & 31;
        tile[jl * 33 + fl] = h[(size_t)(j0 + jl) * 256 + f0 + fl] * wraw[j0 + jl];
    }
    __syncthreads();
    {
        const int fl = t >> 3, cb = t & 7;        // 32 f x 8 cb
        const int phys_cb = cb ^ (fl & 7);
        s8v v;
        #pragma unroll
        for (int lo = 0; lo < 8; ++lo)
            v[lo] = (short)f2bf(tile[(cb * 8 + lo) * 33 + fl]);
        *(s8v*)(gt + (size_t)(f0 + fl) * NN + j0 + phys_cb * 8) = v;
    }
}

// -------- k_fused: part = A @ G (bf16 MFMA, split-K) + S via E2 side-tile --------
// R9: adj register-prefetch pipeline — step+1's int4 adj loads issue right after
// barrier1 and drain at barrier2's vmcnt(0), overlapping the whole MFMA phase
// (vs full ~900-cyc HBM exposure at the top of each step before).
__global__ __launch_bounds__(256) void k_fused(const int* __restrict__ adj,
        const uint16_t* __restrict__ gt, const float* __restrict__ E1,
        const float* __restrict__ E2, uint16_t* __restrict__ part,
        float* __restrict__ Sg, int krange) {
    __shared__ __align__(16) uint16_t As[64 * 72];     // padded (explicit writes)
    __shared__ __align__(16) uint16_t Gs[256 * 64];    // linear (DMA target)
    __shared__ __align__(16) uint16_t GsS[16 * 72];    // E2 row + zeros
    const int ib = blockIdx.x, ks = blockIdx.y;
    const int t = threadIdx.x;
    const int wv = t >> 6, lane = t & 63;
    const int q = lane >> 4, m16 = lane & 15;
    const int i0 = ib * 64, k0 = ks * krange;
    const int ksteps = krange >> 6;
    fx4 acc[4][4];
    #pragma unroll
    for (int a = 0; a < 4; ++a)
        #pragma unroll
        for (int b = 0; b < 4; ++b) acc[a][b] = (fx4){0.f, 0.f, 0.f, 0.f};
    fx4 accS[4];
    #pragma unroll
    for (int a = 0; a < 4; ++a) accS[a] = (fx4){0.f, 0.f, 0.f, 0.f};
    for (int e = t; e < 15 * 72; e += 256) GsS[72 + e] = 0;

    const int fr = lane >> 3, cb = lane & 7;           // DMA lane mapping
    const int ar = t >> 4, ac4 = (t & 15) * 4;         // adj staging mapping
    int4 ra[4];
    #pragma unroll
    for (int p = 0; p < 4; ++p)
        ra[p] = *(const int4*)(adj + (size_t)(i0 + p * 16 + ar) * NN + k0 + ac4);

    for (int step = 0; step < ksteps; ++step) {
        const int kk = k0 + step * 64;
        // ---- As: write prefetched adj regs -> bf16 {0,1} bit-trick ----
        #pragma unroll
        for (int p = 0; p < 4; ++p) {
            uint2 w;
            w.x = (uint32_t)(ra[p].x | (ra[p].y << 16)) * 0x3F80u;
            w.y = (uint32_t)(ra[p].z | (ra[p].w << 16)) * 0x3F80u;
            *(uint2*)(&As[(p * 16 + ar) * 72 + ac4]) = w;
        }
        // ---- Gs: DMA 1 KB (8 rows) per instr, 8 instrs/wave ----
        #pragma unroll
        for (int p = 0; p < 8; ++p) {
            const int f0 = wv * 64 + p * 8;
            const uint16_t* gp = gt + (size_t)(f0 + fr) * NN + kk + cb * 8;
            __builtin_amdgcn_global_load_lds(
                (const __attribute__((address_space(1))) uint32_t*)gp,
                (__attribute__((address_space(3))) uint32_t*)(Gs + f0 * 64),
                16, 0, 0);
        }
        // ---- GsS row 0: E2 chunk in bf16 ----
        if (t < 8) {
            const float* e2p = E2 + kk + t * 8;
            uint32_t* dst = (uint32_t*)(&GsS[t * 8]);
            #pragma unroll
            for (int j = 0; j < 4; ++j)
                dst[j] = (uint32_t)f2bf(e2p[2 * j]) |
                         ((uint32_t)f2bf(e2p[2 * j + 1]) << 16);
        }
        __syncthreads();
        // ---- prefetch next step's adj (drains at barrier2, overlaps MFMA) ----
        if (step + 1 < ksteps) {
            #pragma unroll
            for (int p = 0; p < 4; ++p)
                ra[p] = *(const int4*)(adj + (size_t)(i0 + p * 16 + ar) * NN +
                                       kk + 64 + ac4);
        }
        s8v afr[4][2];
        #pragma unroll
        for (int it = 0; it < 4; ++it)
            #pragma unroll
            for (int kh = 0; kh < 2; ++kh)
                afr[it][kh] = *(const s8v*)(As + (it * 16 + m16) * 72 + kh * 32 + q * 8);
        #pragma unroll
        for (int ft = 0; ft < 4; ++ft) {
            #pragma unroll
            for (int kh = 0; kh < 2; ++kh) {
                const int row = wv * 64 + ft * 16 + m16;
                const int pcb = ((kh << 2) | q) ^ (m16 & 7);   // un-swizzle
                const s8v bfr = *(const s8v*)(Gs + row * 64 + pcb * 8);
                #pragma unroll
                for (int it = 0; it < 4; ++it)
                    acc[it][ft] = __builtin_amdgcn_mfma_f32_16x16x32_bf16(
                        afr[it][kh], bfr, acc[it][ft], 0, 0, 0);
            }
        }
        if (wv == 3) {
            #pragma unroll
            for (int kh = 0; kh < 2; ++kh) {
                const s8v bfrS = *(const s8v*)(GsS + m16 * 72 + kh * 32 + q * 8);
                #pragma unroll
                for (int it = 0; it < 4; ++it)
                    accS[it] = __builtin_amdgcn_mfma_f32_16x16x32_bf16(
                        afr[it][kh], bfrS, accS[it], 0, 0, 0);
            }
        }
        __syncthreads();
    }
    if (wv == 3) {
        float s_local = 0.f;
        #pragma unroll
        for (int it = 0; it < 4; ++it)
            #pragma unroll
            for (int r = 0; r < 4; ++r)
                s_local += accS[it][r] * E1[i0 + it * 16 + q * 4 + r];
        #pragma unroll
        for (int d = 32; d > 0; d >>= 1) s_local += __shfl_down(s_local, d);
        if (lane == 0) atomicAdd(Sg, s_local);
    }
    // bf16 partials; C/D layout: col=lane&15, row=(lane>>4)*4+reg
    uint16_t* dst = part + (size_t)ks * NN * FDIM;
    #pragma unroll
    for (int it = 0; it < 4; ++it) {
        #pragma unroll
        for (int ft = 0; ft < 4; ++ft) {
            const int f = wv * 64 + ft * 16 + m16;
            #pragma unroll
            for (int r = 0; r < 4; ++r) {
                const int i = i0 + it * 16 + q * 4 + r;
                dst[(size_t)i * FDIM + f] = f2bf(acc[it][ft][r]);
            }
        }
    }
}

// -------- k_out: out = relu(sum_k part_k) / S (bf16 partials, 8 f/thread) --------
__global__ __launch_bounds__(256) void k_out(const uint16_t* __restrict__ part,
        const float* __restrict__ Sg, float* __restrict__ out, int nsplit) {
    const size_t idx = ((size_t)blockIdx.x * 256 + threadIdx.x) * 8;
    const float inv = 1.0f / (*Sg);
    float s[8] = {};
    for (int k = 0; k < nsplit; ++k) {
        const s8v v = *(const s8v*)(part + (size_t)k * NN * FDIM + idx);
        #pragma unroll
        for (int j = 0; j < 8; ++j) {
            union { uint32_t u; float f; } cv;
            cv.u = ((uint32_t)(uint16_t)v[j]) << 16;
            s[j] += cv.f;
        }
    }
    fx4 r0, r1;
    #pragma unroll
    for (int j = 0; j < 4; ++j) {
        r0[j] = fmaxf(s[j], 0.f) * inv;
        r1[j] = fmaxf(s[4 + j], 0.f) * inv;
    }
    *(fx4*)(out + idx) = r0;
    *(fx4*)(out + idx + 4) = r1;
}

extern "C" void kernel_launch(void* const* d_in, const int* in_sizes, int n_in,
                              void* d_out, int out_size, void* d_ws, size_t ws_size,
                              hipStream_t stream) {
    const float* x     = (const float*)d_in[0];
    const int*   adj   = (const int*)d_in[1];
    const float* W     = (const float*)d_in[2];
    const float* bias  = (const float*)d_in[3];
    const float* att_w = (const float*)d_in[4];
    // att_b (d_in[5]) cancels exactly in the softmax — unused.
    float* out = (float*)d_out;
    char* ws = (char*)d_ws;
    float*    h    = (float*)(ws + 0);                    // 4 MB
    uint16_t* gt   = (uint16_t*)(ws + (size_t)4194304);   // 2 MB
    float*    a1p  = (float*)(ws + 6291456);              // 64 KB (4 x 4096)
    float*    a2p  = (float*)(ws + 6356992);              // 64 KB
    float*    E1   = (float*)(ws + 6422528);              // 16 KB
    float*    E2   = (float*)(ws + 6438912);              // 16 KB
    float*    wraw = (float*)(ws + 6455296);              // 16 KB
    float*    Sg   = (float*)(ws + 6471680);              // 256 B
    uint16_t* part = (uint16_t*)(ws + 6471936);           // splitk * 2 MB (bf16)

    const size_t avail = (ws_size > 6471936) ? (ws_size - 6471936) : 0;
    int splitk = 1;
    while (splitk < 8 &&
           (size_t)(splitk * 2) * NN * FDIM * sizeof(uint16_t) <= avail)
        splitk <<= 1;
    const int krange = NN / splitk;

    k_h    <<<dim3(64, 4), 512, 0, stream>>>(x, W, bias, att_w, h, a1p, a2p);
    k_prep <<<dim3(1), 1024, 0, stream>>>(a1p, a2p, adj, E1, E2, wraw, Sg);
    k_g    <<<dim3(64, 8), 256, 0, stream>>>(h, wraw, gt);
    k_fused<<<dim3(64, splitk), 256, 0, stream>>>(adj, gt, E1, E2, part, Sg, krange);
    k_out  <<<dim3(512), 256, 0, stream>>>(part, Sg, out, splitk);
}